// Round 2
// baseline (77329.211 us; speedup 1.0000x reference)
//
#include <hip/hip_runtime.h>
#include <math.h>

#define NB   32
#define LEN  1024
#define HIDN 1024
#define H3   3072
#define CND  80
#define EMBD 128

// ws layout in FLOAT elements
#define RWT_OFS   0ull                               // [3072][1024] R_w^T
#define IWT_OFS   (RWT_OFS  + 3072ull*1024)          // [3072][80]   I_W[0:80]^T
#define TAB1_OFS  (IWT_OFS  + 3072ull*80)            // [256][3072]  c_emb proj (+I_b)
#define TAB2_OFS  (TAB1_OFS + 256ull*3072)           // [256][3072]  f_emb proj
#define TAB3_OFS  (TAB2_OFS + 256ull*3072)           // [256][3072]  c_next proj (masked)
#define H_OFS     (TAB3_OFS + 256ull*3072)           // [1025][32][1024] hidden states
#define FOFS      8388608ull                          // 32*1024*256, flogits offset in d_out

__global__ __launch_bounds__(256) void transpose_kc(const float* __restrict__ src,
                                                    float* __restrict__ dst, int K, int C) {
    int idx = blockIdx.x * 256 + threadIdx.x;
    if (idx >= K * C) return;
    int k = idx / C, c = idx % C;
    dst[(size_t)c * K + k] = src[idx];
}

__global__ __launch_bounds__(256) void make_tables(const float* __restrict__ IW,
                                                   const float* __restrict__ Ib,
                                                   const float* __restrict__ cemb,
                                                   const float* __restrict__ femb,
                                                   float* __restrict__ ws) {
    int blk = blockIdx.x;                 // 0..9215 = 3 tables * 256 rows * 12 col-chunks
    int table = blk / 3072;
    int rem = blk % 3072;
    int row = rem / 12;
    int cc = rem % 12;
    int col = cc * 256 + threadIdx.x;
    int ofs = (table == 0) ? CND : (table == 1 ? CND + EMBD : CND + 2 * EMBD);
    const float* emb = (table == 1) ? femb : cemb;
    float acc = 0.f;
    for (int k = 0; k < EMBD; ++k)
        acc += emb[row * EMBD + k] * IW[(size_t)(ofs + k) * H3 + col];
    if (table == 0) acc += Ib[col];
    if (table == 2 && ((col & 1023) < 768)) acc = 0.f;   // mask: c_next only feeds fine quarter
    float* dst = ws + (table == 0 ? TAB1_OFS : (table == 1 ? TAB2_OFS : TAB3_OFS));
    dst[(size_t)row * H3 + col] = acc;
}

#define DOT4(accv, hh, wv) accv += hh.x*wv.x + hh.y*wv.y + hh.z*wv.z + hh.w*wv.w

__global__ __launch_bounds__(256) void scan_step(const float* __restrict__ ws,
                                                 float* __restrict__ Hbuf,
                                                 const float* __restrict__ mel,
                                                 const int* __restrict__ xin,
                                                 const float* __restrict__ Rb,
                                                 int t) {
    int tid = threadIdx.x;
    int b = tid & 31;
    int jl = tid >> 5;
    int j = (blockIdx.x << 3) + jl;

    const float* __restrict__ h = Hbuf + (size_t)t * (NB * HIDN) + (size_t)b * HIDN;
    const float4* hv = (const float4*)h;
    const float4* wu = (const float4*)(ws + RWT_OFS + (size_t)j * HIDN);
    const float4* wr = (const float4*)(ws + RWT_OFS + (size_t)(HIDN + j) * HIDN);
    const float4* we = (const float4*)(ws + RWT_OFS + (size_t)(2 * HIDN + j) * HIDN);

    float au = 0.f, ar = 0.f, ae = 0.f;
#pragma unroll 4
    for (int k = 0; k < HIDN / 4; ++k) {
        float4 hh = hv[k];
        float4 a = wu[k], bb = wr[k], cc = we[k];
        DOT4(au, hh, a);
        DOT4(ar, hh, bb);
        DOT4(ae, hh, cc);
    }

    // mel contribution (K=80)
    const float4* ml = (const float4*)(mel + ((size_t)b * LEN + t) * CND);
    const float4* mu = (const float4*)(ws + IWT_OFS + (size_t)j * CND);
    const float4* mr = (const float4*)(ws + IWT_OFS + (size_t)(HIDN + j) * CND);
    const float4* me = (const float4*)(ws + IWT_OFS + (size_t)(2 * HIDN + j) * CND);
    float xu = 0.f, xr = 0.f, xe = 0.f;
#pragma unroll 4
    for (int k = 0; k < CND / 4; ++k) {
        float4 mm = ml[k];
        float4 a = mu[k], bb = mr[k], cc = me[k];
        DOT4(xu, mm, a);
        DOT4(xr, mm, bb);
        DOT4(xe, mm, cc);
    }

    // embedding-table gathers
    int base = (b * LEN + t) * 2;
    int ci = xin[base];
    int fi = xin[base + 1];
    int cn = xin[(b * LEN + ((t + 1) & (LEN - 1))) * 2];
    const float* t1 = ws + TAB1_OFS + (size_t)ci * H3;
    const float* t2 = ws + TAB2_OFS + (size_t)fi * H3;
    const float* t3 = ws + TAB3_OFS + (size_t)cn * H3;
    xu += t1[j] + t2[j] + t3[j];
    xr += t1[HIDN + j] + t2[HIDN + j] + t3[HIDN + j];
    xe += t1[2 * HIDN + j] + t2[2 * HIDN + j] + t3[2 * HIDN + j];

    float u1 = au + Rb[j];
    float r1 = ar + Rb[HIDN + j];
    float e1 = ae + Rb[2 * HIDN + j];

    float u = 1.f / (1.f + expf(-(u1 + xu)));
    float r = 1.f / (1.f + expf(-(r1 + xr)));
    float e = tanhf(r * e1 + xe);
    float hp = h[j];
    Hbuf[(size_t)(t + 1) * (NB * HIDN) + (size_t)b * HIDN + j] = u * hp + (1.f - u) * e;
}

#define LOADF4(arr, ptr) { float4 _v = *(const float4*)(ptr); arr[0]=_v.x; arr[1]=_v.y; arr[2]=_v.z; arr[3]=_v.w; }

__global__ __launch_bounds__(256) void out_mlp(const float* __restrict__ Hbuf,
                                               const float* __restrict__ O1w, const float* __restrict__ O1b,
                                               const float* __restrict__ O2w, const float* __restrict__ O2b,
                                               const float* __restrict__ O3w, const float* __restrict__ O3b,
                                               const float* __restrict__ O4w, const float* __restrict__ O4b,
                                               float* __restrict__ out) {
    __shared__ float z[16][768];   // 48 KB
    int tid = threadIdx.x;
    int ig = tid >> 6;        // wave id -> rows ig*4..ig*4+3
    int lane = tid & 63;
    int R0 = blockIdx.x * 16;

    const float* yrow[4];
#pragma unroll
    for (int i = 0; i < 4; ++i) {
        int R = R0 + ig * 4 + i;
        int n = R >> 10, l = R & 1023;
        yrow[i] = Hbuf + (size_t)(l + 1) * (NB * HIDN) + (size_t)n * HIDN;
    }

    // ---- layer1-c: z = relu(yc @ O1w + O1b), yc = y[:, :768]
    for (int pass = 0; pass < 3; ++pass) {
        int c = pass * 256 + lane * 4;
        float acc[4][4];
#pragma unroll
        for (int i = 0; i < 4; ++i)
#pragma unroll
            for (int jj = 0; jj < 4; ++jj) acc[i][jj] = O1b[c + jj];
        for (int kk = 0; kk < 768; kk += 4) {
            float w[4][4];
#pragma unroll
            for (int dk = 0; dk < 4; ++dk) LOADF4(w[dk], &O1w[(size_t)(kk + dk) * 768 + c]);
            float ya[4][4];
#pragma unroll
            for (int i = 0; i < 4; ++i) LOADF4(ya[i], &yrow[i][kk]);
#pragma unroll
            for (int i = 0; i < 4; ++i)
#pragma unroll
                for (int dk = 0; dk < 4; ++dk)
#pragma unroll
                    for (int jj = 0; jj < 4; ++jj)
                        acc[i][jj] += ya[i][dk] * w[dk][jj];
        }
#pragma unroll
        for (int i = 0; i < 4; ++i)
#pragma unroll
            for (int jj = 0; jj < 4; ++jj)
                z[ig * 4 + i][c + jj] = fmaxf(acc[i][jj], 0.f);
    }
    __syncthreads();

    // ---- layer2-c: out_c = z @ O2w + O2b  (K=768, 256 cols)
    {
        int c = lane * 4;
        float acc[4][4];
#pragma unroll
        for (int i = 0; i < 4; ++i)
#pragma unroll
            for (int jj = 0; jj < 4; ++jj) acc[i][jj] = O2b[c + jj];
        for (int kk = 0; kk < 768; kk += 4) {
            float w[4][4];
#pragma unroll
            for (int dk = 0; dk < 4; ++dk) LOADF4(w[dk], &O2w[(size_t)(kk + dk) * 256 + c]);
            float za[4][4];
#pragma unroll
            for (int i = 0; i < 4; ++i) LOADF4(za[i], &z[ig * 4 + i][kk]);
#pragma unroll
            for (int i = 0; i < 4; ++i)
#pragma unroll
                for (int dk = 0; dk < 4; ++dk)
#pragma unroll
                    for (int jj = 0; jj < 4; ++jj)
                        acc[i][jj] += za[i][dk] * w[dk][jj];
        }
#pragma unroll
        for (int i = 0; i < 4; ++i) {
            int R = R0 + ig * 4 + i;
#pragma unroll
            for (int jj = 0; jj < 4; ++jj)
                out[(size_t)R * 256 + c + jj] = acc[i][jj];
        }
    }
    __syncthreads();

    // ---- layer1-f: z2 = relu(yf @ O3w + O3b), yf = y[:, 768:1024]  (reuse z cols 0..255)
    {
        int c = lane * 4;
        float acc[4][4];
#pragma unroll
        for (int i = 0; i < 4; ++i)
#pragma unroll
            for (int jj = 0; jj < 4; ++jj) acc[i][jj] = O3b[c + jj];
        for (int kk = 0; kk < 256; kk += 4) {
            float w[4][4];
#pragma unroll
            for (int dk = 0; dk < 4; ++dk) LOADF4(w[dk], &O3w[(size_t)(kk + dk) * 256 + c]);
            float ya[4][4];
#pragma unroll
            for (int i = 0; i < 4; ++i) LOADF4(ya[i], &yrow[i][768 + kk]);
#pragma unroll
            for (int i = 0; i < 4; ++i)
#pragma unroll
                for (int dk = 0; dk < 4; ++dk)
#pragma unroll
                    for (int jj = 0; jj < 4; ++jj)
                        acc[i][jj] += ya[i][dk] * w[dk][jj];
        }
        __syncthreads();   // ensure layer2-c reads of z are done before overwrite
#pragma unroll
        for (int i = 0; i < 4; ++i)
#pragma unroll
            for (int jj = 0; jj < 4; ++jj)
                z[ig * 4 + i][c + jj] = fmaxf(acc[i][jj], 0.f);
    }
    __syncthreads();

    // ---- layer2-f: out_f = z2 @ O4w + O4b  (K=256)
    {
        int c = lane * 4;
        float acc[4][4];
#pragma unroll
        for (int i = 0; i < 4; ++i)
#pragma unroll
            for (int jj = 0; jj < 4; ++jj) acc[i][jj] = O4b[c + jj];
        for (int kk = 0; kk < 256; kk += 4) {
            float w[4][4];
#pragma unroll
            for (int dk = 0; dk < 4; ++dk) LOADF4(w[dk], &O4w[(size_t)(kk + dk) * 256 + c]);
            float za[4][4];
#pragma unroll
            for (int i = 0; i < 4; ++i) LOADF4(za[i], &z[ig * 4 + i][kk]);
#pragma unroll
            for (int i = 0; i < 4; ++i)
#pragma unroll
                for (int dk = 0; dk < 4; ++dk)
#pragma unroll
                    for (int jj = 0; jj < 4; ++jj)
                        acc[i][jj] += za[i][dk] * w[dk][jj];
        }
#pragma unroll
        for (int i = 0; i < 4; ++i) {
            int R = R0 + ig * 4 + i;
#pragma unroll
            for (int jj = 0; jj < 4; ++jj)
                out[FOFS + (size_t)R * 256 + c + jj] = acc[i][jj];
        }
    }
}

extern "C" void kernel_launch(void* const* d_in, const int* in_sizes, int n_in,
                              void* d_out, int out_size, void* d_ws, size_t ws_size,
                              hipStream_t stream) {
    const int*   x    = (const int*)d_in[0];
    const float* mel  = (const float*)d_in[1];
    const float* Rw   = (const float*)d_in[2];
    const float* Rb   = (const float*)d_in[3];
    const float* IW   = (const float*)d_in[4];
    const float* Ib   = (const float*)d_in[5];
    const float* O1w  = (const float*)d_in[6];
    const float* O1b  = (const float*)d_in[7];
    const float* O2w  = (const float*)d_in[8];
    const float* O2b  = (const float*)d_in[9];
    const float* O3w  = (const float*)d_in[10];
    const float* O3b  = (const float*)d_in[11];
    const float* O4w  = (const float*)d_in[12];
    const float* O4b  = (const float*)d_in[13];
    const float* cemb = (const float*)d_in[14];
    const float* femb = (const float*)d_in[15];
    float* ws  = (float*)d_ws;
    float* out = (float*)d_out;

    // prep: transposes + tables + h0 = 0
    transpose_kc<<<(1024 * 3072 + 255) / 256, 256, 0, stream>>>(Rw, ws + RWT_OFS, 1024, 3072);
    transpose_kc<<<(80 * 3072 + 255) / 256, 256, 0, stream>>>(IW, ws + IWT_OFS, 80, 3072);
    make_tables<<<9216, 256, 0, stream>>>(IW, Ib, cemb, femb, ws);
    hipMemsetAsync((void*)(ws + H_OFS), 0, NB * HIDN * sizeof(float), stream);

    // sequential GRU scan
    for (int t = 0; t < LEN; ++t)
        scan_step<<<128, 256, 0, stream>>>(ws, ws + H_OFS, mel, x, Rb, t);

    // output MLPs
    out_mlp<<<2048, 256, 0, stream>>>(ws + H_OFS, O1w, O1b, O2w, O2b, O3w, O3b, O4w, O4b, out);
}

// Round 3
// 10708.140 us; speedup vs baseline: 7.2215x; 7.2215x over previous
//
#include <hip/hip_runtime.h>
#include <hip/hip_bf16.h>
#include <math.h>

typedef __attribute__((ext_vector_type(4))) float vf4;
typedef __attribute__((ext_vector_type(8))) short vbf8;
typedef __attribute__((ext_vector_type(8))) unsigned short vus8;

#define NWG   128
#define LEN   1024
#define H3    3072
#define CND   80
#define EMBD  128
#define NFRAG 35      // K = 1120 = 35*32 (1024 h + 80 mel + 1 bias + 15 pad)

// ---- ws byte offsets (total ~92.1 MB, well under known-safe 157 MB) ----
#define TAB1_B  0ull
#define TAB2_B  (TAB1_B + 786432ull*4)
#define TAB3_B  (TAB2_B + 786432ull*4)
#define BF_B    (TAB3_B + 786432ull*4)            // bfrag: 128wg*2tile*35frag*512 = 4,587,520 bf16
#define MELA_B  (BF_B   + 4587520ull*2)           // melA : 1024t*2m*3frag*512    = 3,145,728 bf16
#define AF_B    (MELA_B + 3145728ull*2)           // Afrag: 1025t*64frag*512      = 33,587,200 bf16
#define CNT_B   (AF_B   + 33587200ull*2)
#define FOFS    8388608ull                         // flogits offset in d_out (32*1024*256)

// ============================ prep kernels ============================

// embedding-projection tables: tab[g*1024+j] contributions, I_b folded into tab1,
// c_next mask folded into tab3 (zero except last quarter of each gate block)
__global__ __launch_bounds__(256) void make_tables(const float* __restrict__ IW,
                                                   const float* __restrict__ Ib,
                                                   const float* __restrict__ cemb,
                                                   const float* __restrict__ femb,
                                                   float* __restrict__ tab1,
                                                   float* __restrict__ tab2,
                                                   float* __restrict__ tab3) {
    int blk = blockIdx.x;                 // 3 tables * 256 rows * 12 col-chunks
    int table = blk / 3072;
    int rem = blk % 3072;
    int row = rem / 12;
    int cc = rem % 12;
    int col = cc * 256 + threadIdx.x;
    int ofs = CND + table * EMBD;
    const float* emb = (table == 1) ? femb : cemb;
    float acc = 0.f;
    for (int k = 0; k < EMBD; ++k)
        acc += emb[row * EMBD + k] * IW[(size_t)(ofs + k) * H3 + col];
    if (table == 0) acc += Ib[col];
    if (table == 2 && ((col & 1023) < 768)) acc = 0.f;
    float* dst = (table == 0) ? tab1 : (table == 1 ? tab2 : tab3);
    dst[(size_t)row * H3 + col] = acc;
}

// B in MFMA fragment order. Per wg (8 j's): tile n=0 cols = [u x8 | r x8],
// tile n=1 cols = [e1 x8 | e2 x8]. K rows: 0..1023 = R_w; 1024..1103 = IW mel rows;
// 1104 = bias slot (R_b); rest pad 0. e1 = h-part + Rb (multiplied by r later),
// e2 = mel-part only (tables added at gate time).
__global__ __launch_bounds__(256) void build_bfrag(const float* __restrict__ Rw,
                                                   const float* __restrict__ IW,
                                                   const float* __restrict__ Rb,
                                                   unsigned short* __restrict__ Bf) {
    long idx = (long)blockIdx.x * 256 + threadIdx.x;   // < 4,587,520 exact
    int elem = idx & 7;
    int lane = (idx >> 3) & 63;
    int kk   = (int)((idx >> 9) % 35);
    int n    = (int)((idx / (512 * 35)) & 1);
    int wg   = (int)(idx / (512 * 35 * 2));
    int c    = lane & 15;
    int k    = kk * 32 + ((lane >> 4) & 3) * 8 + elem;
    int jj   = wg * 8 + (c & 7);
    float v = 0.f;
    if (n == 0) {
        int col = (c >> 3) * 1024 + jj;          // u (c<8) or r (c>=8)
        if (k < 1024)       v = Rw[(size_t)k * H3 + col];
        else if (k < 1104)  v = IW[(size_t)(k - 1024) * H3 + col];
        else if (k == 1104) v = Rb[col];
    } else {
        if ((c >> 3) == 0) {                     // e1
            if (k < 1024)       v = Rw[(size_t)k * H3 + 2048 + jj];
            else if (k == 1104) v = Rb[2048 + jj];
        } else {                                 // e2
            if (k >= 1024 && k < 1104) v = IW[(size_t)(k - 1024) * H3 + 2048 + jj];
        }
    }
    __hip_bfloat16 hb = __float2bfloat16(v);
    Bf[idx] = *(unsigned short*)&hb;
}

// mel (+ bias 1.0) in A-fragment order per t: [m][kfrag 0..2][lane][elem]
__global__ __launch_bounds__(256) void build_melA(const float* __restrict__ mel,
                                                  unsigned short* __restrict__ MelA) {
    long idx = (long)blockIdx.x * 256 + threadIdx.x;   // < 3,145,728 exact
    int elem = idx & 7;
    int lane = (idx >> 3) & 63;
    int kkm  = (int)((idx >> 9) % 3);
    int m    = (int)((idx / 1536) & 1);
    int t    = (int)(idx / 3072);
    int b    = m * 16 + (lane & 15);
    int km   = kkm * 32 + ((lane >> 4) & 3) * 8 + elem;
    float v = (km < CND) ? mel[((size_t)b * LEN + t) * CND + km] : (km == CND ? 1.f : 0.f);
    __hip_bfloat16 hb = __float2bfloat16(v);
    MelA[idx] = *(unsigned short*)&hb;
}

// ============================ persistent scan ============================
// 128 WGs x 256 thr. Weights stationary in LDS (bf16 frags). h state in f32
// registers (thread <-> (b,j) fixed). Per-step h broadcast via Afrag[t] (fresh
// address per step => no cross-XCD stale-line hazard for plain loads).
__global__ __launch_bounds__(256) void scan_persist(const unsigned short* __restrict__ Bf,
                                                    const unsigned short* __restrict__ MelA,
                                                    unsigned short* __restrict__ Af,
                                                    const float* __restrict__ tab1,
                                                    const float* __restrict__ tab2,
                                                    const float* __restrict__ tab3,
                                                    const int* __restrict__ xin,
                                                    unsigned int* __restrict__ cnt) {
    __shared__ unsigned short Bs[2 * 35 * 512];   // 71,680 B
    __shared__ float ex[32][36];                  // pre-act exchange, padded

    int tid = threadIdx.x;
    int wg  = blockIdx.x;

    // stage this WG's B fragments into LDS (one-time)
    {
        const vus8* src = (const vus8*)(Bf + (size_t)wg * (2 * 35 * 512));
        vus8* dst = (vus8*)Bs;
        for (int i = tid; i < (2 * 35 * 512) / 8; i += 256) dst[i] = src[i];
    }

    int lane = tid & 63;
    int wv = tid >> 6;
    int m = wv >> 1, n = wv & 1;                  // MFMA role: tile (m,n)

    int gb = tid >> 3, gjl = tid & 7;             // gate role: (b, j-local)
    int gj = wg * 8 + gjl;
    float hreg = 0.f;
    size_t wbase = (size_t)(((gb >> 4) * 32 + (gj >> 5)) * 512 +
                            ((gb & 15) + 16 * ((gj >> 3) & 3)) * 8 + (gj & 7));

    const unsigned short* Bn = Bs + (n * 35) * 512 + lane * 8;
    __syncthreads();

#pragma unroll 1
    for (int t = 0; t < LEN; ++t) {
        // ---- prefetch per-step indices + table gathers (gate role) ----
        int ci = xin[(gb * LEN + t) * 2];
        int fi = xin[(gb * LEN + t) * 2 + 1];
        int cn = xin[(gb * LEN + ((t + 1) & (LEN - 1))) * 2];
        float t1u = tab1[(size_t)ci * H3 + gj];
        float t2u = tab2[(size_t)fi * H3 + gj];
        float t3u = tab3[(size_t)cn * H3 + gj];
        float t1r = tab1[(size_t)ci * H3 + 1024 + gj];
        float t2r = tab2[(size_t)fi * H3 + 1024 + gj];
        float t3r = tab3[(size_t)cn * H3 + 1024 + gj];
        float t1e = tab1[(size_t)ci * H3 + 2048 + gj];
        float t2e = tab2[(size_t)fi * H3 + 2048 + gj];
        float t3e = tab3[(size_t)cn * H3 + 2048 + gj];

        // ---- GEMV via MFMA: D(32x32) = A(32x1120) * B(1120x32) ----
        const unsigned short* Ah = Af + (size_t)t * 32768 + (size_t)(m * 32) * 512 + lane * 8;
        const unsigned short* Am = MelA + (size_t)t * 3072 + (size_t)(m * 3) * 512 + lane * 8;
        vf4 acc0 = {0.f, 0.f, 0.f, 0.f}, acc1 = {0.f, 0.f, 0.f, 0.f};
#pragma unroll
        for (int kk = 0; kk < 32; kk += 2) {
            vbf8 a0 = *(const vbf8*)(Ah + kk * 512);
            vbf8 b0 = *(const vbf8*)(Bn + kk * 512);
            acc0 = __builtin_amdgcn_mfma_f32_16x16x32_bf16(a0, b0, acc0, 0, 0, 0);
            vbf8 a1 = *(const vbf8*)(Ah + (kk + 1) * 512);
            vbf8 b1 = *(const vbf8*)(Bn + (kk + 1) * 512);
            acc1 = __builtin_amdgcn_mfma_f32_16x16x32_bf16(a1, b1, acc1, 0, 0, 0);
        }
#pragma unroll
        for (int kk = 0; kk < 3; ++kk) {
            vbf8 a = *(const vbf8*)(Am + kk * 512);
            vbf8 b = *(const vbf8*)(Bn + (32 + kk) * 512);
            acc0 = __builtin_amdgcn_mfma_f32_16x16x32_bf16(a, b, acc0, 0, 0, 0);
        }
        vf4 acc = acc0 + acc1;

        // ---- exchange pre-activations (C layout: col=lane&15, row=(lane>>4)*4+r) ----
#pragma unroll
        for (int r = 0; r < 4; ++r)
            ex[m * 16 + ((lane >> 4) * 4 + r)][n * 16 + (lane & 15)] = acc[r];
        __syncthreads();

        // ---- gates + state update ----
        float gu  = ex[gb][gjl]      + t1u + t2u + t3u;
        float gr  = ex[gb][8 + gjl]  + t1r + t2r + t3r;
        float e1  = ex[gb][16 + gjl];
        float ge2 = ex[gb][24 + gjl] + t1e + t2e + t3e;
        float u  = 1.f / (1.f + expf(-gu));
        float r_ = 1.f / (1.f + expf(-gr));
        float e  = tanhf(r_ * e1 + ge2);
        hreg = u * hreg + (1.f - u) * e;
        __hip_bfloat16 hb = __float2bfloat16(hreg);
        Af[(size_t)(t + 1) * 32768 + wbase] = *(unsigned short*)&hb;

        // ---- global barrier: release (fence+add) / acquire (spin) ----
        __syncthreads();   // drains all waves' stores (vmcnt 0 before s_barrier)
        if (tid == 0) {
            __threadfence();   // agent fence: flush L2 so stores reach coherence point
            __hip_atomic_fetch_add(cnt, 1u, __ATOMIC_RELEASE, __HIP_MEMORY_SCOPE_AGENT);
            unsigned target = (unsigned)(t + 1) * NWG;
            while (__hip_atomic_load(cnt, __ATOMIC_ACQUIRE, __HIP_MEMORY_SCOPE_AGENT) < target)
                __builtin_amdgcn_s_sleep(4);
        }
        __syncthreads();
    }
}

// ============================ output MLPs ============================
#define LOADF4(arr, ptr) { float4 _v = *(const float4*)(ptr); arr[0]=_v.x; arr[1]=_v.y; arr[2]=_v.z; arr[3]=_v.w; }

__device__ __forceinline__ void load_y8(const unsigned short* __restrict__ Af,
                                        int tslot, int b, int kk, float* o) {
    size_t off = (size_t)tslot * 32768 +
                 (size_t)(((b >> 4) * 32 + (kk >> 5)) * 512) +
                 (size_t)(((b & 15) + 16 * ((kk >> 3) & 3)) * 8);
    vus8 v = *(const vus8*)(Af + off);
#pragma unroll
    for (int e = 0; e < 8; ++e) o[e] = __uint_as_float(((unsigned)v[e]) << 16);
}

__global__ __launch_bounds__(256) void out_mlp(const unsigned short* __restrict__ Af,
                                               const float* __restrict__ O1w, const float* __restrict__ O1b,
                                               const float* __restrict__ O2w, const float* __restrict__ O2b,
                                               const float* __restrict__ O3w, const float* __restrict__ O3b,
                                               const float* __restrict__ O4w, const float* __restrict__ O4b,
                                               float* __restrict__ out) {
    __shared__ float z[16][768];   // 48 KB
    int tid = threadIdx.x;
    int ig = tid >> 6;
    int lane = tid & 63;
    int R0 = blockIdx.x * 16;

    int rb[4], rt[4];
#pragma unroll
    for (int i = 0; i < 4; ++i) {
        int R = R0 + ig * 4 + i;
        rb[i] = R >> 10;            // batch
        rt[i] = (R & 1023) + 1;     // Afrag slot
    }

    // ---- layer1-c: z = relu(yc @ O1w + O1b), yc = y[:, :768]
    for (int pass = 0; pass < 3; ++pass) {
        int c = pass * 256 + lane * 4;
        float acc[4][4];
#pragma unroll
        for (int i = 0; i < 4; ++i)
#pragma unroll
            for (int jj = 0; jj < 4; ++jj) acc[i][jj] = O1b[c + jj];
        for (int kk = 0; kk < 768; kk += 8) {
            float w[8][4];
#pragma unroll
            for (int dk = 0; dk < 8; ++dk) LOADF4(w[dk], &O1w[(size_t)(kk + dk) * 768 + c]);
            float ya[4][8];
#pragma unroll
            for (int i = 0; i < 4; ++i) load_y8(Af, rt[i], rb[i], kk, ya[i]);
#pragma unroll
            for (int i = 0; i < 4; ++i)
#pragma unroll
                for (int dk = 0; dk < 8; ++dk)
#pragma unroll
                    for (int jj = 0; jj < 4; ++jj)
                        acc[i][jj] += ya[i][dk] * w[dk][jj];
        }
#pragma unroll
        for (int i = 0; i < 4; ++i)
#pragma unroll
            for (int jj = 0; jj < 4; ++jj)
                z[ig * 4 + i][c + jj] = fmaxf(acc[i][jj], 0.f);
    }
    __syncthreads();

    // ---- layer2-c: out_c = z @ O2w + O2b
    {
        int c = lane * 4;
        float acc[4][4];
#pragma unroll
        for (int i = 0; i < 4; ++i)
#pragma unroll
            for (int jj = 0; jj < 4; ++jj) acc[i][jj] = O2b[c + jj];
        for (int kk = 0; kk < 768; kk += 4) {
            float w[4][4];
#pragma unroll
            for (int dk = 0; dk < 4; ++dk) LOADF4(w[dk], &O2w[(size_t)(kk + dk) * 256 + c]);
            float za[4][4];
#pragma unroll
            for (int i = 0; i < 4; ++i) LOADF4(za[i], &z[ig * 4 + i][kk]);
#pragma unroll
            for (int i = 0; i < 4; ++i)
#pragma unroll
                for (int dk = 0; dk < 4; ++dk)
#pragma unroll
                    for (int jj = 0; jj < 4; ++jj)
                        acc[i][jj] += za[i][dk] * w[dk][jj];
        }
#pragma unroll
        for (int i = 0; i < 4; ++i) {
            int R = R0 + ig * 4 + i;
#pragma unroll
            for (int jj = 0; jj < 4; ++jj)
                out[(size_t)R * 256 + c + jj] = acc[i][jj];
        }
    }
    __syncthreads();

    // ---- layer1-f: z2 = relu(yf @ O3w + O3b), yf = y[:, 768:1024]
    {
        int c = lane * 4;
        float acc[4][4];
#pragma unroll
        for (int i = 0; i < 4; ++i)
#pragma unroll
            for (int jj = 0; jj < 4; ++jj) acc[i][jj] = O3b[c + jj];
        for (int kk = 0; kk < 256; kk += 8) {
            float w[8][4];
#pragma unroll
            for (int dk = 0; dk < 8; ++dk) LOADF4(w[dk], &O3w[(size_t)(kk + dk) * 256 + c]);
            float ya[4][8];
#pragma unroll
            for (int i = 0; i < 4; ++i) load_y8(Af, rt[i], rb[i], 768 + kk, ya[i]);
#pragma unroll
            for (int i = 0; i < 4; ++i)
#pragma unroll
                for (int dk = 0; dk < 8; ++dk)
#pragma unroll
                    for (int jj = 0; jj < 4; ++jj)
                        acc[i][jj] += ya[i][dk] * w[dk][jj];
        }
        __syncthreads();
#pragma unroll
        for (int i = 0; i < 4; ++i)
#pragma unroll
            for (int jj = 0; jj < 4; ++jj)
                z[ig * 4 + i][c + jj] = fmaxf(acc[i][jj], 0.f);
    }
    __syncthreads();

    // ---- layer2-f: out_f = z2 @ O4w + O4b
    {
        int c = lane * 4;
        float acc[4][4];
#pragma unroll
        for (int i = 0; i < 4; ++i)
#pragma unroll
            for (int jj = 0; jj < 4; ++jj) acc[i][jj] = O4b[c + jj];
        for (int kk = 0; kk < 256; kk += 4) {
            float w[4][4];
#pragma unroll
            for (int dk = 0; dk < 4; ++dk) LOADF4(w[dk], &O4w[(size_t)(kk + dk) * 256 + c]);
            float za[4][4];
#pragma unroll
            for (int i = 0; i < 4; ++i) LOADF4(za[i], &z[ig * 4 + i][kk]);
#pragma unroll
            for (int i = 0; i < 4; ++i)
#pragma unroll
                for (int dk = 0; dk < 4; ++dk)
#pragma unroll
                    for (int jj = 0; jj < 4; ++jj)
                        acc[i][jj] += za[i][dk] * w[dk][jj];
        }
#pragma unroll
        for (int i = 0; i < 4; ++i) {
            int R = R0 + ig * 4 + i;
#pragma unroll
            for (int jj = 0; jj < 4; ++jj)
                out[FOFS + (size_t)R * 256 + c + jj] = acc[i][jj];
        }
    }
}

// ============================ launch ============================
extern "C" void kernel_launch(void* const* d_in, const int* in_sizes, int n_in,
                              void* d_out, int out_size, void* d_ws, size_t ws_size,
                              hipStream_t stream) {
    const int*   x    = (const int*)d_in[0];
    const float* mel  = (const float*)d_in[1];
    const float* Rw   = (const float*)d_in[2];
    const float* Rb   = (const float*)d_in[3];
    const float* IW   = (const float*)d_in[4];
    const float* Ib   = (const float*)d_in[5];
    const float* O1w  = (const float*)d_in[6];
    const float* O1b  = (const float*)d_in[7];
    const float* O2w  = (const float*)d_in[8];
    const float* O2b  = (const float*)d_in[9];
    const float* O3w  = (const float*)d_in[10];
    const float* O3b  = (const float*)d_in[11];
    const float* O4w  = (const float*)d_in[12];
    const float* O4b  = (const float*)d_in[13];
    const float* cemb = (const float*)d_in[14];
    const float* femb = (const float*)d_in[15];
    char* wsb = (char*)d_ws;
    float* out = (float*)d_out;

    float* tab1 = (float*)(wsb + TAB1_B);
    float* tab2 = (float*)(wsb + TAB2_B);
    float* tab3 = (float*)(wsb + TAB3_B);
    unsigned short* Bf   = (unsigned short*)(wsb + BF_B);
    unsigned short* MelA = (unsigned short*)(wsb + MELA_B);
    unsigned short* Af   = (unsigned short*)(wsb + AF_B);
    unsigned int*   cnt  = (unsigned int*)(wsb + CNT_B);

    make_tables<<<9216, 256, 0, stream>>>(IW, Ib, cemb, femb, tab1, tab2, tab3);
    build_bfrag<<<17920, 256, 0, stream>>>(Rw, IW, Rb, Bf);
    build_melA<<<12288, 256, 0, stream>>>(mel, MelA);
    hipMemsetAsync((void*)Af, 0, 65536, stream);   // h0 = 0
    hipMemsetAsync((void*)cnt, 0, 4, stream);      // barrier counter

    scan_persist<<<NWG, 256, 0, stream>>>(Bf, MelA, Af, tab1, tab2, tab3, x, cnt);

    out_mlp<<<2048, 256, 0, stream>>>(Af, O1w, O1b, O2w, O2b, O3w, O3b, O4w, O4b, out);
}

// Round 4
// 6304.118 us; speedup vs baseline: 12.2665x; 1.6986x over previous
//
#include <hip/hip_runtime.h>
#include <hip/hip_bf16.h>
#include <math.h>

typedef __attribute__((ext_vector_type(4))) float vf4;
typedef __attribute__((ext_vector_type(8))) short vbf8;
typedef __attribute__((ext_vector_type(8))) unsigned short vus8;

#define NWG   64
#define NTHR  512
#define LEN   1024
#define H3    3072
#define CND   80
#define EMBD  128

// ---- ws byte offsets ----
#define TAB1_B  0ull
#define TAB2_B  (TAB1_B + 786432ull*4)
#define TAB3_B  (TAB2_B + 786432ull*4)
#define BF_B    (TAB3_B + 786432ull*4)            // bfrag: 128oct*2which*35frag*512 bf16
#define MELA_B  (BF_B   + 4587520ull*2)           // melA : 1024t*2m*3frag*512 bf16
#define AF_B    (MELA_B + 3145728ull*2)           // Afrag: 1025t*64frag*512 bf16
#define CNT_B   (AF_B   + 33587200ull*2)          // 4 counters, 256B apart
#define FOFS    8388608ull                        // flogits offset in d_out

// ============================ prep kernels (unchanged) ============================

__global__ __launch_bounds__(256) void make_tables(const float* __restrict__ IW,
                                                   const float* __restrict__ Ib,
                                                   const float* __restrict__ cemb,
                                                   const float* __restrict__ femb,
                                                   float* __restrict__ tab1,
                                                   float* __restrict__ tab2,
                                                   float* __restrict__ tab3) {
    int blk = blockIdx.x;
    int table = blk / 3072;
    int rem = blk % 3072;
    int row = rem / 12;
    int cc = rem % 12;
    int col = cc * 256 + threadIdx.x;
    int ofs = CND + table * EMBD;
    const float* emb = (table == 1) ? femb : cemb;
    float acc = 0.f;
    for (int k = 0; k < EMBD; ++k)
        acc += emb[row * EMBD + k] * IW[(size_t)(ofs + k) * H3 + col];
    if (table == 0) acc += Ib[col];
    if (table == 2 && ((col & 1023) < 768)) acc = 0.f;
    float* dst = (table == 0) ? tab1 : (table == 1 ? tab2 : tab3);
    dst[(size_t)row * H3 + col] = acc;
}

// B frag layout: [octet 0..127][which 0..1][kk 0..34][lane 0..63][elem 0..7]
// which=0: cols [u x8 | r x8]; which=1: cols [e1 x8 | e2 x8]; K rows 0..1023=R_w,
// 1024..1103=IW mel rows, 1104=bias (R_b), rest 0.
__global__ __launch_bounds__(256) void build_bfrag(const float* __restrict__ Rw,
                                                   const float* __restrict__ IW,
                                                   const float* __restrict__ Rb,
                                                   unsigned short* __restrict__ Bf) {
    long idx = (long)blockIdx.x * 256 + threadIdx.x;
    int elem = idx & 7;
    int lane = (idx >> 3) & 63;
    int kk   = (int)((idx >> 9) % 35);
    int n    = (int)((idx / (512 * 35)) & 1);
    int oc   = (int)(idx / (512 * 35 * 2));
    int c    = lane & 15;
    int k    = kk * 32 + ((lane >> 4) & 3) * 8 + elem;
    int jj   = oc * 8 + (c & 7);
    float v = 0.f;
    if (n == 0) {
        int col = (c >> 3) * 1024 + jj;
        if (k < 1024)       v = Rw[(size_t)k * H3 + col];
        else if (k < 1104)  v = IW[(size_t)(k - 1024) * H3 + col];
        else if (k == 1104) v = Rb[col];
    } else {
        if ((c >> 3) == 0) {
            if (k < 1024)       v = Rw[(size_t)k * H3 + 2048 + jj];
            else if (k == 1104) v = Rb[2048 + jj];
        } else {
            if (k >= 1024 && k < 1104) v = IW[(size_t)(k - 1024) * H3 + 2048 + jj];
        }
    }
    __hip_bfloat16 hb = __float2bfloat16(v);
    Bf[idx] = *(unsigned short*)&hb;
}

__global__ __launch_bounds__(256) void build_melA(const float* __restrict__ mel,
                                                  unsigned short* __restrict__ MelA) {
    long idx = (long)blockIdx.x * 256 + threadIdx.x;
    int elem = idx & 7;
    int lane = (idx >> 3) & 63;
    int kkm  = (int)((idx >> 9) % 3);
    int m    = (int)((idx / 1536) & 1);
    int t    = (int)(idx / 3072);
    int b    = m * 16 + (lane & 15);
    int km   = kkm * 32 + ((lane >> 4) & 3) * 8 + elem;
    float v = (km < CND) ? mel[((size_t)b * LEN + t) * CND + km] : (km == CND ? 1.f : 0.f);
    __hip_bfloat16 hb = __float2bfloat16(v);
    MelA[idx] = *(unsigned short*)&hb;
}

// ============================ persistent scan ============================
// 64 WGs x 512 thr (8 waves). B stationary in VGPRs (35 vbf8/wave). h state in
// registers. h broadcast: coherent (agent, write-through) packed u32 stores;
// consumers use normal cached loads made safe by ONE agent-acquire fence per
// step (invalidates L2; all Af[t] lines then fetch fresh from the coherence pt).
__global__ __launch_bounds__(512, 2) void scan_persist(const unsigned short* __restrict__ Bf,
                                                       const unsigned short* __restrict__ MelA,
                                                       unsigned short* __restrict__ Af,
                                                       const float* __restrict__ tab1,
                                                       const float* __restrict__ tab2,
                                                       const float* __restrict__ tab3,
                                                       const int* __restrict__ xin,
                                                       unsigned int* __restrict__ cnt) {
    __shared__ float ex[32][68];   // pre-act exchange: 32 b x 64 cols, padded

    int tid = threadIdx.x;
    int wg  = blockIdx.x;
    int lane = tid & 63;
    int wv = tid >> 6;            // 0..7
    int m  = wv >> 2;             // A half (batch 0-15 / 16-31)
    int ng = wv & 3;              // n-tile within WG
    int p  = ng >> 1;             // octet within WG
    int which = ng & 1;           // 0: u|r, 1: e1|e2
    int oct = wg * 2 + p;         // global 8-j octet

    // ---- stationary B fragments -> VGPRs (one-time) ----
    vbf8 Breg[35];
    {
        const unsigned short* Bp = Bf + (((size_t)oct * 2 + which) * 35) * 512 + lane * 8;
#pragma unroll
        for (int kk = 0; kk < 35; ++kk)
            Breg[kk] = *(const vbf8*)(Bp + kk * 512);
    }

    // gate role
    int gb = tid >> 4, gjl = tid & 15;
    int gj = wg * 16 + gjl;
    float hreg = 0.f;
    size_t wbase = (size_t)(((gb >> 4) * 32 + (gj >> 5)) * 512 +
                            ((gb & 15) + 16 * ((gj >> 3) & 3)) * 8 + (gj & 7));

#pragma unroll 1
    for (int t = 0; t < LEN; ++t) {
        // ---- A loads (normal cached; fresh post-inv) ----
        const unsigned short* Ah = Af + (size_t)t * 32768 + (size_t)(m * 32) * 512 + lane * 8;
        const unsigned short* Am = MelA + (size_t)t * 3072 + (size_t)(m * 3) * 512 + lane * 8;

        // ---- table gathers (consumed late; latency hides under MFMA) ----
        int ci = xin[(gb * LEN + t) * 2];
        int fi = xin[(gb * LEN + t) * 2 + 1];
        int cn = xin[(gb * LEN + ((t + 1) & (LEN - 1))) * 2];
        float t1u = tab1[(size_t)ci * H3 + gj];
        float t2u = tab2[(size_t)fi * H3 + gj];
        float t3u = tab3[(size_t)cn * H3 + gj];
        float t1r = tab1[(size_t)ci * H3 + 1024 + gj];
        float t2r = tab2[(size_t)fi * H3 + 1024 + gj];
        float t3r = tab3[(size_t)cn * H3 + 1024 + gj];
        float t1e = tab1[(size_t)ci * H3 + 2048 + gj];
        float t2e = tab2[(size_t)fi * H3 + 2048 + gj];
        float t3e = tab3[(size_t)cn * H3 + 2048 + gj];

        // ---- D(16x16) = A(16x1120) x B(1120x16), two independent chains ----
        vf4 acc0 = {0.f, 0.f, 0.f, 0.f}, acc1 = {0.f, 0.f, 0.f, 0.f};
#pragma unroll
        for (int kk = 0; kk < 32; kk += 2) {
            vbf8 a0 = *(const vbf8*)(Ah + kk * 512);
            acc0 = __builtin_amdgcn_mfma_f32_16x16x32_bf16(a0, Breg[kk], acc0, 0, 0, 0);
            vbf8 a1 = *(const vbf8*)(Ah + (kk + 1) * 512);
            acc1 = __builtin_amdgcn_mfma_f32_16x16x32_bf16(a1, Breg[kk + 1], acc1, 0, 0, 0);
        }
#pragma unroll
        for (int kk = 0; kk < 3; ++kk) {
            vbf8 a = *(const vbf8*)(Am + kk * 512);
            acc0 = __builtin_amdgcn_mfma_f32_16x16x32_bf16(a, Breg[32 + kk], acc0, 0, 0, 0);
        }
        vf4 acc = acc0 + acc1;

        // ---- exchange pre-activations (C: col=lane&15, row=(lane>>4)*4+r) ----
#pragma unroll
        for (int r = 0; r < 4; ++r)
            ex[m * 16 + ((lane >> 4) * 4 + r)][ng * 16 + (lane & 15)] = acc[r];
        __syncthreads();

        // ---- gates + state update ----
        int pp = gjl >> 3, jo = gjl & 7;
        float gu  = ex[gb][pp * 32 + jo]      + t1u + t2u + t3u;
        float gr  = ex[gb][pp * 32 + 8 + jo]  + t1r + t2r + t3r;
        float e1  = ex[gb][pp * 32 + 16 + jo];
        float ge2 = ex[gb][pp * 32 + 24 + jo] + t1e + t2e + t3e;
        float u  = 1.f / (1.f + expf(-gu));
        float r_ = 1.f / (1.f + expf(-gr));
        float e  = tanhf(r_ * e1 + ge2);
        hreg = u * hreg + (1.f - u) * e;

        // ---- coherent packed store of h (write-through; pair via shfl) ----
        __hip_bfloat16 hb = __float2bfloat16(hreg);
        int myv = (int)(*(unsigned short*)&hb);
        int nbv = __shfl_xor(myv, 1);
        if ((tid & 1) == 0) {
            unsigned int pk = ((unsigned)myv & 0xffffu) | ((unsigned)nbv << 16);
            __hip_atomic_store((unsigned int*)(Af + (size_t)(t + 1) * 32768 + wbase), pk,
                               __ATOMIC_RELAXED, __HIP_MEMORY_SCOPE_AGENT);
        }

        // ---- global barrier ----
        __syncthreads();   // per-wave vmcnt(0): all coherent stores acked
        if (tid == 0) {
            __hip_atomic_fetch_add(&cnt[(wg & 3) * 64], 1u,
                                   __ATOMIC_RELEASE, __HIP_MEMORY_SCOPE_AGENT);
            unsigned tgt = (unsigned)(t + 1) * 16;   // 16 WGs per counter
            for (;;) {
                unsigned c0 = __hip_atomic_load(&cnt[0],   __ATOMIC_RELAXED, __HIP_MEMORY_SCOPE_AGENT);
                unsigned c1 = __hip_atomic_load(&cnt[64],  __ATOMIC_RELAXED, __HIP_MEMORY_SCOPE_AGENT);
                unsigned c2 = __hip_atomic_load(&cnt[128], __ATOMIC_RELAXED, __HIP_MEMORY_SCOPE_AGENT);
                unsigned c3 = __hip_atomic_load(&cnt[192], __ATOMIC_RELAXED, __HIP_MEMORY_SCOPE_AGENT);
                if (c0 >= tgt && c1 >= tgt && c2 >= tgt && c3 >= tgt) break;
                __builtin_amdgcn_s_sleep(1);
            }
            __builtin_amdgcn_fence(__ATOMIC_ACQUIRE, "agent");  // ONE L2 inv per step
        }
        __syncthreads();
        asm volatile("" ::: "memory");   // no load hoisting above the barrier
    }
}

// ============================ output MLPs (unchanged) ============================
#define LOADF4(arr, ptr) { float4 _v = *(const float4*)(ptr); arr[0]=_v.x; arr[1]=_v.y; arr[2]=_v.z; arr[3]=_v.w; }

__device__ __forceinline__ void load_y8(const unsigned short* __restrict__ Af,
                                        int tslot, int b, int kk, float* o) {
    size_t off = (size_t)tslot * 32768 +
                 (size_t)(((b >> 4) * 32 + (kk >> 5)) * 512) +
                 (size_t)(((b & 15) + 16 * ((kk >> 3) & 3)) * 8);
    vus8 v = *(const vus8*)(Af + off);
#pragma unroll
    for (int e = 0; e < 8; ++e) o[e] = __uint_as_float(((unsigned)v[e]) << 16);
}

__global__ __launch_bounds__(256) void out_mlp(const unsigned short* __restrict__ Af,
                                               const float* __restrict__ O1w, const float* __restrict__ O1b,
                                               const float* __restrict__ O2w, const float* __restrict__ O2b,
                                               const float* __restrict__ O3w, const float* __restrict__ O3b,
                                               const float* __restrict__ O4w, const float* __restrict__ O4b,
                                               float* __restrict__ out) {
    __shared__ float z[16][768];
    int tid = threadIdx.x;
    int ig = tid >> 6;
    int lane = tid & 63;
    int R0 = blockIdx.x * 16;

    int rb[4], rt[4];
#pragma unroll
    for (int i = 0; i < 4; ++i) {
        int R = R0 + ig * 4 + i;
        rb[i] = R >> 10;
        rt[i] = (R & 1023) + 1;
    }

    for (int pass = 0; pass < 3; ++pass) {
        int c = pass * 256 + lane * 4;
        float acc[4][4];
#pragma unroll
        for (int i = 0; i < 4; ++i)
#pragma unroll
            for (int jj = 0; jj < 4; ++jj) acc[i][jj] = O1b[c + jj];
        for (int kk = 0; kk < 768; kk += 8) {
            float w[8][4];
#pragma unroll
            for (int dk = 0; dk < 8; ++dk) LOADF4(w[dk], &O1w[(size_t)(kk + dk) * 768 + c]);
            float ya[4][8];
#pragma unroll
            for (int i = 0; i < 4; ++i) load_y8(Af, rt[i], rb[i], kk, ya[i]);
#pragma unroll
            for (int i = 0; i < 4; ++i)
#pragma unroll
                for (int dk = 0; dk < 8; ++dk)
#pragma unroll
                    for (int jj = 0; jj < 4; ++jj)
                        acc[i][jj] += ya[i][dk] * w[dk][jj];
        }
#pragma unroll
        for (int i = 0; i < 4; ++i)
#pragma unroll
            for (int jj = 0; jj < 4; ++jj)
                z[ig * 4 + i][c + jj] = fmaxf(acc[i][jj], 0.f);
    }
    __syncthreads();

    {
        int c = lane * 4;
        float acc[4][4];
#pragma unroll
        for (int i = 0; i < 4; ++i)
#pragma unroll
            for (int jj = 0; jj < 4; ++jj) acc[i][jj] = O2b[c + jj];
        for (int kk = 0; kk < 768; kk += 4) {
            float w[4][4];
#pragma unroll
            for (int dk = 0; dk < 4; ++dk) LOADF4(w[dk], &O2w[(size_t)(kk + dk) * 256 + c]);
            float za[4][4];
#pragma unroll
            for (int i = 0; i < 4; ++i) LOADF4(za[i], &z[ig * 4 + i][kk]);
#pragma unroll
            for (int i = 0; i < 4; ++i)
#pragma unroll
                for (int dk = 0; dk < 4; ++dk)
#pragma unroll
                    for (int jj = 0; jj < 4; ++jj)
                        acc[i][jj] += za[i][dk] * w[dk][jj];
        }
#pragma unroll
        for (int i = 0; i < 4; ++i) {
            int R = R0 + ig * 4 + i;
#pragma unroll
            for (int jj = 0; jj < 4; ++jj)
                out[(size_t)R * 256 + c + jj] = acc[i][jj];
        }
    }
    __syncthreads();

    {
        int c = lane * 4;
        float acc[4][4];
#pragma unroll
        for (int i = 0; i < 4; ++i)
#pragma unroll
            for (int jj = 0; jj < 4; ++jj) acc[i][jj] = O3b[c + jj];
        for (int kk = 0; kk < 256; kk += 8) {
            float w[8][4];
#pragma unroll
            for (int dk = 0; dk < 8; ++dk) LOADF4(w[dk], &O3w[(size_t)(kk + dk) * 256 + c]);
            float ya[4][8];
#pragma unroll
            for (int i = 0; i < 4; ++i) load_y8(Af, rt[i], rb[i], 768 + kk, ya[i]);
#pragma unroll
            for (int i = 0; i < 4; ++i)
#pragma unroll
                for (int dk = 0; dk < 8; ++dk)
#pragma unroll
                    for (int jj = 0; jj < 4; ++jj)
                        acc[i][jj] += ya[i][dk] * w[dk][jj];
        }
        __syncthreads();
#pragma unroll
        for (int i = 0; i < 4; ++i)
#pragma unroll
            for (int jj = 0; jj < 4; ++jj)
                z[ig * 4 + i][c + jj] = fmaxf(acc[i][jj], 0.f);
    }
    __syncthreads();

    {
        int c = lane * 4;
        float acc[4][4];
#pragma unroll
        for (int i = 0; i < 4; ++i)
#pragma unroll
            for (int jj = 0; jj < 4; ++jj) acc[i][jj] = O4b[c + jj];
        for (int kk = 0; kk < 256; kk += 4) {
            float w[4][4];
#pragma unroll
            for (int dk = 0; dk < 4; ++dk) LOADF4(w[dk], &O4w[(size_t)(kk + dk) * 256 + c]);
            float za[4][4];
#pragma unroll
            for (int i = 0; i < 4; ++i) LOADF4(za[i], &z[ig * 4 + i][kk]);
#pragma unroll
            for (int i = 0; i < 4; ++i)
#pragma unroll
                for (int dk = 0; dk < 4; ++dk)
#pragma unroll
                    for (int jj = 0; jj < 4; ++jj)
                        acc[i][jj] += za[i][dk] * w[dk][jj];
        }
#pragma unroll
        for (int i = 0; i < 4; ++i) {
            int R = R0 + ig * 4 + i;
#pragma unroll
            for (int jj = 0; jj < 4; ++jj)
                out[FOFS + (size_t)R * 256 + c + jj] = acc[i][jj];
        }
    }
}

// ============================ launch ============================
extern "C" void kernel_launch(void* const* d_in, const int* in_sizes, int n_in,
                              void* d_out, int out_size, void* d_ws, size_t ws_size,
                              hipStream_t stream) {
    const int*   x    = (const int*)d_in[0];
    const float* mel  = (const float*)d_in[1];
    const float* Rw   = (const float*)d_in[2];
    const float* Rb   = (const float*)d_in[3];
    const float* IW   = (const float*)d_in[4];
    const float* Ib   = (const float*)d_in[5];
    const float* O1w  = (const float*)d_in[6];
    const float* O1b  = (const float*)d_in[7];
    const float* O2w  = (const float*)d_in[8];
    const float* O2b  = (const float*)d_in[9];
    const float* O3w  = (const float*)d_in[10];
    const float* O3b  = (const float*)d_in[11];
    const float* O4w  = (const float*)d_in[12];
    const float* O4b  = (const float*)d_in[13];
    const float* cemb = (const float*)d_in[14];
    const float* femb = (const float*)d_in[15];
    char* wsb = (char*)d_ws;
    float* out = (float*)d_out;

    float* tab1 = (float*)(wsb + TAB1_B);
    float* tab2 = (float*)(wsb + TAB2_B);
    float* tab3 = (float*)(wsb + TAB3_B);
    unsigned short* Bf   = (unsigned short*)(wsb + BF_B);
    unsigned short* MelA = (unsigned short*)(wsb + MELA_B);
    unsigned short* Af   = (unsigned short*)(wsb + AF_B);
    unsigned int*   cnt  = (unsigned int*)(wsb + CNT_B);

    make_tables<<<9216, 256, 0, stream>>>(IW, Ib, cemb, femb, tab1, tab2, tab3);
    build_bfrag<<<17920, 256, 0, stream>>>(Rw, IW, Rb, Bf);
    build_melA<<<12288, 256, 0, stream>>>(mel, MelA);
    hipMemsetAsync((void*)Af, 0, 65536, stream);   // h0 = 0
    hipMemsetAsync((void*)cnt, 0, 1024, stream);   // barrier counters

    scan_persist<<<NWG, NTHR, 0, stream>>>(Bf, MelA, Af, tab1, tab2, tab3, x, cnt);

    out_mlp<<<2048, 256, 0, stream>>>(Af, O1w, O1b, O2w, O2b, O3w, O3b, O4w, O4b, out);
}